// Round 12
// baseline (213.487 us; speedup 1.0000x reference)
//
#include <hip/hip_runtime.h>
#include <hip/hip_bf16.h>
#include <stdint.h>

// Round 13: revert to R11's 16-wave GEMM (best: QKV 113.5us) and remove the
// mid-tile sched_barrier(0). R12's 8-wave config regressed (TLP at 2/SIMD
// beats the LDS-traffic saving). R11's residual 40% is the intra-tile convoy:
// all waves read-then-MFMA in lockstep because the sched_barrier between
// MFMA-k0 and reads-k1 forbids interleave. Removing it lets the compiler
// issue each k1 ds_read right after the last k0 MFMA consuming that register
// (WAR-ordered, zero extra VGPRs) -- dripping reads into the LDS queue while
// the matrix pipe drains. First sched_barrier (stage pinning, R4 lesson)
// stays. Everything else identical to R11.
//
// ws layout (bytes):
//   xb   : [0, 32MB)  bf16 [M, C]   (reused as attn)
//   wqb  : 32MB + 2MB each: wkb, wvb, wob   (wq..wv contiguous = fused [3C, C])
//   q    : 40MB  k : 72MB  v : 104MB   bf16 [M, C]
//   kvp  : 136MB f32 [8][64][64][64];  ksp : +8MB f32 [8][64][64]
//   kvT  : 144MB+128KB  bf16 [64][80][64]  (640 KB)

#define B_ 4
#define T_ 4096
#define C_ 1024
#define H_ 16
#define D_ 64
#define M_ (B_*T_)
#define TCH 512
#define K_ 1024
#define NT_ (K_/64)          // 16 K-tiles of BK=64

using u16 = unsigned short;
using u32 = unsigned int;

typedef __attribute__((ext_vector_type(8))) short bf16x8;
typedef __attribute__((ext_vector_type(4))) float f32x4;

static __device__ __forceinline__ u16 f2bf(float f){
  u32 u = __float_as_uint(f);
  u32 r = (u + 0x7fffu + ((u >> 16) & 1u)) >> 16;   // RNE, no NaN here
  return (u16)r;
}
static __device__ __forceinline__ void unpack8(uint4 u, float* f){
  f[0]=__uint_as_float(u.x<<16); f[1]=__uint_as_float(u.x&0xffff0000u);
  f[2]=__uint_as_float(u.y<<16); f[3]=__uint_as_float(u.y&0xffff0000u);
  f[4]=__uint_as_float(u.z<<16); f[5]=__uint_as_float(u.z&0xffff0000u);
  f[6]=__uint_as_float(u.w<<16); f[7]=__uint_as_float(u.w&0xffff0000u);
}
static __device__ __forceinline__ void gload16(const u16* g, u16* l){
  __builtin_amdgcn_global_load_lds(
      (const __attribute__((address_space(1))) void*)g,
      (__attribute__((address_space(3))) void*)l, 16, 0, 0);
}

#define FENCE() asm volatile("" ::: "memory")
#define BAR() do { FENCE(); __builtin_amdgcn_s_barrier(); FENCE(); } while(0)

// ---------------- fp32 -> bf16 convert: x + 4 weights in ONE launch ----------
__global__ __launch_bounds__(256) void cvt_all(
    const float* __restrict__ x,
    const float* __restrict__ s0, const float* __restrict__ s1,
    const float* __restrict__ s2, const float* __restrict__ s3,
    u16* __restrict__ xb,
    u16* __restrict__ d0, u16* __restrict__ d1,
    u16* __restrict__ d2, u16* __restrict__ d3)
{
  const float* s; u16* d; int bi;
  if (blockIdx.x < 8192) { s = x; d = xb; bi = blockIdx.x; }
  else {
    const int seg = (blockIdx.x - 8192) >> 9;
    bi = (blockIdx.x - 8192) & 511;
    s = seg==0?s0:seg==1?s1:seg==2?s2:s3;
    d = seg==0?d0:seg==1?d1:seg==2?d2:d3;
  }
  const int i = (bi*256 + threadIdx.x) * 8;
  const float4 a = *(const float4*)(s + i);
  const float4 b = *(const float4*)(s + i + 4);
  uint4 o;
  o.x = (u32)f2bf(a.x) | ((u32)f2bf(a.y) << 16);
  o.y = (u32)f2bf(a.z) | ((u32)f2bf(a.w) << 16);
  o.z = (u32)f2bf(b.x) | ((u32)f2bf(b.y) << 16);
  o.w = (u32)f2bf(b.z) | ((u32)f2bf(b.w) << 16);
  *(uint4*)(d + i) = o;
}

// ---------------- 256x256 / BK=64 / 16-wave / A3+B2-ring MFMA GEMM -----------
// Y[M,N] = X[M,K] @ W[N,K]^T + b.  1024 threads = 16 waves (4M x 4N), wave
// tile 64x64.  LDS 160 KiB (u16 units): A slot s at s*16384 (s=0..2, halves
// +8192), B slot s at 49152 + s*16384 (s=0..1, halves +8192).
// T2 swizzle: logical 16B-chunk c of row r at phys chunk c^(r&7); staged via
// linear global_load_lds dest + inverse-swizzled global source.
// Per K-tile v (A slot v%3, B slot v%2), ONE barrier:
//   reads k0 (8, into a/b); stageB(v+1)->(v+1)%2; stageA(v+2)->(v+2)%3;
//   sched_barrier (pin stages); { MFMA k0 / reads k1 / MFMA k1 } freely
//   scheduled (compiler interleaves k1 ds_reads among k0 MFMAs via register
//   reuse order); vmcnt(2) [tail (0)/none]; BAR
// Live set: 8 frags (32 VGPR) + acc (64) + addr -> fits 128/wave, no spill.
// FIFO at tile end: outstanding = A(v+1), B(v+1), A(v+2) (6 gloads);
// vmcnt(2) drains A(v+1)+B(v+1), leaves A(v+2) flying (T4: never 0 in loop).
// WAR safety: a wave's reads of a slot complete at its lgkm wait (before its
// MFMAs, before it reaches the tile BAR); stages issue only after the prior
// BAR and target slots last read one tile earlier. Proven by R10/R11 passes.
template<bool FUSED>
__global__ __launch_bounds__(1024, 4) void gemm256(
    const u16* __restrict__ X, const u16* __restrict__ Wm,
    const float* __restrict__ b0, const float* __restrict__ b1,
    const float* __restrict__ b2,
    void* __restrict__ Y0, void* __restrict__ Y1, void* __restrict__ Y2)
{
  extern __shared__ __align__(16) u16 lds[];   // 163840 B
  const int tid  = threadIdx.x;
  const int lane = tid & 63, w = tid >> 6;
  const int wr = w >> 2, wc = w & 3;           // wave grid 4 x 4
  const int fr = lane & 15, hi = lane >> 4;

  // patch-based XCD mapping: 4bm x 4bn patches (~4MB working set per patch =
  // fits one XCD L2). Bijective: FUSED 768 = 8*6*16; !FUSED 256 = 8*2*16.
  const int xcd = blockIdx.x & 7;
  const int r   = blockIdx.x >> 3;
  const int ppx = gridDim.x >> 7;              // patches per XCD (6 or 2)
  const int patchIdx = xcd * ppx + (r >> 4);
  const int wi = r & 15;
  const int pm = FUSED ? (patchIdx & 15) : patchIdx;
  const int pn = FUSED ? (patchIdx >> 4) : 0;
  const int bm = pm*4 + (wi & 3);
  const int bn = pn*4 + (wi >> 2);

  // staging: thread t covers LDS bytes t*16 of a 128x64 half-tile;
  // row = t>>3 (0..127), phys chunk t&7 holds logical chunk (t&7)^(row&7).
  const int srow = tid >> 3;
  const int scc  = (tid & 7) ^ (srow & 7);
  const u16* gA = X  + (size_t)(bm*256 + srow)*K_ + scc*8;
  const u16* gB = Wm + (size_t)(bn*256 + srow)*K_ + scc*8;

  auto stageA = [&](int slot, int kt){
    const size_t ko = (size_t)kt * 64;
    gload16(gA + ko,                  lds + slot*16384 + tid*8);
    gload16(gA + (size_t)128*K_ + ko, lds + slot*16384 + 8192 + tid*8);
  };
  auto stageB = [&](int slot, int kt){
    const size_t ko = (size_t)kt * 64;
    gload16(gB + ko,                  lds + 49152 + slot*16384 + tid*8);
    gload16(gB + (size_t)128*K_ + ko, lds + 49152 + slot*16384 + 8192 + tid*8);
  };

  f32x4 acc[4][4] = {};
  const int cx0 = (hi ^ (fr & 7)) << 3;        // k-half 0 chunk (u16 offset)
  const int cx1 = ((4 + hi) ^ (fr & 7)) << 3;  // k-half 1 chunk
  // per-wave LDS fragment lane bases (slot/row-step added as immediates)
  const u16* Abase = lds + (wr >> 1)*8192 + ((wr & 1)*64 + fr)*64;
  const u16* Bbase = lds + 49152 + (wc >> 1)*8192 + ((wc & 1)*64 + fr)*64;

  // prologue FIFO: A(0)x2, B(0)x2, A(1)x2 -> vmcnt(2) drains A0,B0, leaves A1.
  // B(1) is staged at tile 0 (steady-state pattern).
  stageA(0,0); stageB(0,0);
  stageA(1,1);
  asm volatile("s_waitcnt vmcnt(2)" ::: "memory");
  BAR();

  // MODE: 0 = stage B(v+1)+A(v+2), vmcnt(2); 1 = stage B(v+1) only, vmcnt(0);
  //       2 = final (no stage, no wait, no BAR)
#define TILE(AS, BS, BSG, BKT, ASG, AKT, MODE) \
  { \
    bf16x8 a[4], b[4]; \
    _Pragma("unroll") \
    for (int i = 0; i < 4; ++i) a[i] = *(const bf16x8*)&Abase[(AS)*16384 + cx0 + i*1024]; \
    _Pragma("unroll") \
    for (int j = 0; j < 4; ++j) b[j] = *(const bf16x8*)&Bbase[(BS)*16384 + cx0 + j*1024]; \
    if (MODE != 2) stageB((BSG), (BKT)); \
    if (MODE == 0) stageA((ASG), (AKT)); \
    __builtin_amdgcn_sched_barrier(0); \
    __builtin_amdgcn_s_setprio(1); \
    _Pragma("unroll") \
    for (int i = 0; i < 4; ++i) \
      _Pragma("unroll") \
      for (int j = 0; j < 4; ++j) \
        acc[i][j] = __builtin_amdgcn_mfma_f32_16x16x32_bf16(a[i], b[j], acc[i][j], 0, 0, 0); \
    __builtin_amdgcn_s_setprio(0); \
    _Pragma("unroll") \
    for (int i = 0; i < 4; ++i) a[i] = *(const bf16x8*)&Abase[(AS)*16384 + cx1 + i*1024]; \
    _Pragma("unroll") \
    for (int j = 0; j < 4; ++j) b[j] = *(const bf16x8*)&Bbase[(BS)*16384 + cx1 + j*1024]; \
    __builtin_amdgcn_s_setprio(1); \
    _Pragma("unroll") \
    for (int i = 0; i < 4; ++i) \
      _Pragma("unroll") \
      for (int j = 0; j < 4; ++j) \
        acc[i][j] = __builtin_amdgcn_mfma_f32_16x16x32_bf16(a[i], b[j], acc[i][j], 0, 0, 0); \
    __builtin_amdgcn_s_setprio(0); \
    if (MODE == 0)      asm volatile("s_waitcnt vmcnt(2)" ::: "memory"); \
    else if (MODE == 1) asm volatile("s_waitcnt vmcnt(0)" ::: "memory"); \
    if (MODE != 2) BAR(); \
  }

  // v = 0..15: A slot v%3, B slot v%2; stage B(v+1)->(v+1)%2, A(v+2)->(v+2)%3
  TILE(0,0, 1, 1, 2, 2, 0)   // v=0
  TILE(1,1, 0, 2, 0, 3, 0)   // v=1
  TILE(2,0, 1, 3, 1, 4, 0)   // v=2
  TILE(0,1, 0, 4, 2, 5, 0)   // v=3
  TILE(1,0, 1, 5, 0, 6, 0)   // v=4
  TILE(2,1, 0, 6, 1, 7, 0)   // v=5
  TILE(0,0, 1, 7, 2, 8, 0)   // v=6
  TILE(1,1, 0, 8, 0, 9, 0)   // v=7
  TILE(2,0, 1, 9, 1,10, 0)   // v=8
  TILE(0,1, 0,10, 2,11, 0)   // v=9
  TILE(1,0, 1,11, 0,12, 0)   // v=10
  TILE(2,1, 0,12, 1,13, 0)   // v=11
  TILE(0,0, 1,13, 2,14, 0)   // v=12
  TILE(1,1, 0,14, 0,15, 0)   // v=13
  TILE(2,0, 1,15, 0, 0, 1)   // v=14: stage B(15) only, drain all
  TILE(0,1, 0, 0, 0, 0, 2)   // v=15: final

#undef TILE

  // epilogue: C/D layout col = lane&15 (n), row = (lane>>4)*4 + reg (m).
  // j innermost: per (i,r2) the wave's stores cover one contiguous
  // 128B (bf16) / 256B (fp32) span -> full-line writes, no RMW.
  const int nloc = wc*64 + fr;
  if constexpr (FUSED) {
    const int sel  = bn >> 2;                  // uniform per block
    const int colb = (bn & 3)*256 + nloc;
    const float* bp = (sel == 0 ? b0 : sel == 1 ? b1 : b2);
    u16* Y = (u16*)(sel == 0 ? Y0 : sel == 1 ? Y1 : Y2);
    const bool elu = sel < 2;
    float bb[4];
    #pragma unroll
    for (int j = 0; j < 4; ++j) bb[j] = bp[colb + j*16];
    #pragma unroll
    for (int i = 0; i < 4; ++i) {
      #pragma unroll
      for (int r2 = 0; r2 < 4; ++r2) {
        const size_t row = (size_t)(bm*256 + wr*64 + i*16 + hi*4 + r2);
        u16* yp = Y + row*1024 + colb;
        #pragma unroll
        for (int j = 0; j < 4; ++j) {
          float vv = acc[i][j][r2] + bb[j];
          if (elu) vv = (vv > 0.0f) ? (vv + 1.0f) : __expf(vv);   // elu(x)+1
          yp[j*16] = f2bf(vv);
        }
      }
    }
  } else {
    const int n0 = bn*256 + nloc;
    float bb[4];
    #pragma unroll
    for (int j = 0; j < 4; ++j) bb[j] = b0[n0 + j*16];
    float* Y = (float*)Y0;
    #pragma unroll
    for (int i = 0; i < 4; ++i) {
      #pragma unroll
      for (int r2 = 0; r2 < 4; ++r2) {
        const size_t row = (size_t)(bm*256 + wr*64 + i*16 + hi*4 + r2);
        float* yp = Y + row*1024 + n0;
        #pragma unroll
        for (int j = 0; j < 4; ++j)
          yp[j*16] = acc[i][j][r2] + bb[j];
      }
    }
  }
}

// ---------------- kv partial (unchanged) -------------------------------------
__global__ __launch_bounds__(256) void kv_partial(
    const u16* __restrict__ Kb, const u16* __restrict__ Vb,
    float* __restrict__ kvp, float* __restrict__ ksp)
{
  const int tid = threadIdx.x;
  const int bh = blockIdx.x;
  const int b = bh >> 4, h = bh & 15;
  const int chunk = blockIdx.y;
  __shared__ float kbuf[32][68];
  __shared__ float vbuf[32][68];
  float acc[4][4] = {};
  float ksl = 0.0f;
  const int d0 = (tid >> 4) << 2, e0 = (tid & 15) << 2;
  const int lrow = tid >> 3, lcol = (tid & 7) << 3;

  for (int s = 0; s < TCH/32; ++s) {
    const int t = chunk*TCH + s*32;
    {
      const size_t base = ((size_t)(b*T_ + t + lrow))*C_ + h*64 + lcol;
      const uint4 ku = *(const uint4*)(Kb + base);
      const uint4 vu = *(const uint4*)(Vb + base);
      float kf[8], vf[8];
      unpack8(ku, kf); unpack8(vu, vf);
      #pragma unroll
      for (int j = 0; j < 8; ++j) { kbuf[lrow][lcol+j] = kf[j]; vbuf[lrow][lcol+j] = vf[j]; }
    }
    __syncthreads();
    if (tid < 64) {
      #pragma unroll
      for (int tt = 0; tt < 32; ++tt) ksl += kbuf[tt][tid];
    }
    #pragma unroll
    for (int tt = 0; tt < 32; ++tt) {
      const float4 ka = *(const float4*)&kbuf[tt][d0];
      const float4 va = *(const float4*)&vbuf[tt][e0];
      const float kr[4] = {ka.x, ka.y, ka.z, ka.w};
      const float vr[4] = {va.x, va.y, va.z, va.w};
      #pragma unroll
      for (int i = 0; i < 4; ++i)
        #pragma unroll
        for (int j = 0; j < 4; ++j)
          acc[i][j] = fmaf(kr[i], vr[j], acc[i][j]);
    }
    __syncthreads();
  }

  float* dst = kvp + ((size_t)(chunk*64 + bh))*4096;
  #pragma unroll
  for (int i = 0; i < 4; ++i)
    *(float4*)&dst[(d0+i)*64 + e0] = make_float4(acc[i][0], acc[i][1], acc[i][2], acc[i][3]);
  if (tid < 64) ksp[((size_t)(chunk*64 + bh))*64 + tid] = ksl;
}

// ---------------- kv reduce -> bf16 kvT[bh][80][64] (row 64 = ksum) ----------
__global__ __launch_bounds__(256) void kv_reduce(
    const float* __restrict__ kvp, const float* __restrict__ ksp,
    u16* __restrict__ kvT)
{
  const int idx = blockIdx.x*256 + threadIdx.x;
  if (idx < 262144) {                          // idx = bh*4096 + d*64 + e
    float s = 0.0f;
    #pragma unroll
    for (int c = 0; c < 8; ++c) s += kvp[(size_t)c*262144 + idx];
    const int bh = idx >> 12, d = (idx >> 6) & 63, e = idx & 63;
    kvT[(size_t)bh*5120 + e*64 + d] = f2bf(s);
  } else if (idx < 266240) {                   // bh*64 + d -> ksum row
    const int i2 = idx - 262144;
    float s = 0.0f;
    #pragma unroll
    for (int c = 0; c < 8; ++c) s += ksp[(size_t)c*4096 + i2];
    const int bh = i2 >> 6, d = i2 & 63;
    kvT[(size_t)bh*5120 + 4096 + d] = f2bf(s);
  } else if (idx < 266240 + 64*15*64) {        // zero rows 65..79
    const int i3 = idx - 266240;
    const int bh = i3 / 960, rd = i3 - bh*960;
    kvT[(size_t)bh*5120 + 4160 + rd] = 0;
  }
}

// ---------------- attn_norm via MFMA (unchanged) -----------------------------
__global__ __launch_bounds__(256) void attn_norm_mfma(
    const u16* __restrict__ Qb, const u16* __restrict__ kvT,
    u16* __restrict__ attn)
{
  __shared__ __align__(16) u16 qs[256*64];     // 32 KB
  const int tid = threadIdx.x;
  const int lane = tid & 63, w = tid >> 6;
  const int bh = blockIdx.x;
  const int b = bh >> 4, h = bh & 15;
  const int tt = blockIdx.y;                   // 16 tiles of 256 rows
  const int fr = lane & 15, hi = lane >> 4;

  // stage q tile: linear LDS dest, inverse-swizzled global source (rule #21)
  {
    const int srow = tid >> 3, scc = tid & 7;
    #pragma unroll
    for (int r = 0; r < 8; ++r) {
      const int row = r*32 + srow;
      const u16* src = Qb + ((size_t)(b*T_ + tt*256 + row))*C_ + h*64
                         + ((scc ^ (row & 7)) << 3);
      gload16(src, qs + tid*8 + r*2048);
    }
  }

  // B-fragments direct from global while staging is in flight
  const u16* kvb = kvT + (size_t)bh*5120;
  bf16x8 bv[5][2];
  #pragma unroll
  for (int j = 0; j < 5; ++j) {
    const int row = (j < 4) ? (j*16 + fr) : (64 + fr);
    bv[j][0] = *(const bf16x8*)&kvb[row*64 + hi*8];
    bv[j][1] = *(const bf16x8*)&kvb[row*64 + 32 + hi*8];
  }

  __syncthreads();                             // drains vmcnt: q tile visible

  f32x4 accN[4][4] = {};
  f32x4 accD[4] = {};
  #pragma unroll
  for (int kh = 0; kh < 2; ++kh) {
    const int cx = ((kh*4 + hi) ^ (fr & 7)) << 3;
    bf16x8 a[4];
    #pragma unroll
    for (int i = 0; i < 4; ++i)
      a[i] = *(const bf16x8*)&qs[(w*64 + i*16 + fr)*64 + cx];
    #pragma unroll
    for (int i = 0; i < 4; ++i) {
      #pragma unroll
      for (int j = 0; j < 4; ++j)
        accN[i][j] = __builtin_amdgcn_mfma_f32_16x16x32_bf16(a[i], bv[j][kh], accN[i][j], 0, 0, 0);
      accD[i] = __builtin_amdgcn_mfma_f32_16x16x32_bf16(a[i], bv[4][kh], accD[i], 0, 0, 0);
    }
  }

  // epilogue: den in col 0 (fr==0 lanes) of accD; broadcast within hi-group
  #pragma unroll
  for (int i = 0; i < 4; ++i) {
    #pragma unroll
    for (int r = 0; r < 4; ++r) {
      const float den = __shfl(accD[i][r], lane & 0x30);
      const float inv = 1.0f / fmaxf(den, 1e-6f);
      const size_t row = (size_t)(b*T_ + tt*256 + w*64 + i*16 + hi*4 + r);
      u16* yp = attn + row*1024 + h*64 + fr;
      #pragma unroll
      for (int j = 0; j < 4; ++j)
        yp[j*16] = f2bf(accN[i][j][r] * inv);
    }
  }
}

extern "C" void kernel_launch(void* const* d_in, const int* in_sizes, int n_in,
                              void* d_out, int out_size, void* d_ws, size_t ws_size,
                              hipStream_t stream)
{
  (void)in_sizes; (void)n_in; (void)out_size; (void)ws_size;
  const float* x  = (const float*)d_in[0];
  const float* Wq = (const float*)d_in[1];
  const float* bq = (const float*)d_in[2];
  const float* Wk = (const float*)d_in[3];
  const float* bk = (const float*)d_in[4];
  const float* Wv = (const float*)d_in[5];
  const float* bv = (const float*)d_in[6];
  const float* Wo = (const float*)d_in[7];
  const float* bo = (const float*)d_in[8];
  float* out = (float*)d_out;
  char* ws = (char*)d_ws;

  const size_t MB = 1024*1024;
  u16*   xb   = (u16*)(ws);                       // 32MB
  u16*   wqb  = (u16*)(ws + 32*MB);               // 2MB each; wq..wv = fused [3072,1024]
  u16*   wkb  = (u16*)(ws + 34*MB);
  u16*   wvb  = (u16*)(ws + 36*MB);
  u16*   wob  = (u16*)(ws + 38*MB);
  u16*   q    = (u16*)(ws + 40*MB);               // 32MB
  u16*   k    = (u16*)(ws + 72*MB);               // 32MB
  u16*   v    = (u16*)(ws + 104*MB);              // 32MB
  float* kvp  = (float*)(ws + 136*MB);            // 8MB
  float* ksp  = (float*)(ws + 144*MB);            // 128KB
  u16*   kvT  = (u16*)(ws + 144*MB + 131072);     // 640KB bf16 [64][80][64]
  u16*   attn = xb;  // xb dead after the fused QKV GEMM

  static bool s_attr_done = false;
  if (!s_attr_done) {
    (void)hipFuncSetAttribute(reinterpret_cast<const void*>(gemm256<true>),
                              hipFuncAttributeMaxDynamicSharedMemorySize, 163840);
    (void)hipFuncSetAttribute(reinterpret_cast<const void*>(gemm256<false>),
                              hipFuncAttributeMaxDynamicSharedMemorySize, 163840);
    s_attr_done = true;
  }

  dim3 blk(256);
  // x: 8192 blocks; 4 weights: 512 blocks each
  cvt_all<<<dim3(8192 + 4*512), blk, 0, stream>>>(
      x, Wq, Wk, Wv, Wo, xb, wqb, wkb, wvb, wob);

  // fused QKV projection: Y[16384, 3072] split into q/k/v, ELU+1 on q,k
  gemm256<true><<<dim3(64*12), dim3(1024), 163840, stream>>>(
      xb, wqb, bq, bk, bv, q, k, v);

  kv_partial<<<dim3(B_*H_, T_/TCH), blk, 0, stream>>>(k, v, kvp, ksp);
  kv_reduce<<<dim3(1280), blk, 0, stream>>>(kvp, ksp, kvT);
  attn_norm_mfma<<<dim3(B_*H_, T_/256), blk, 0, stream>>>(q, kvT, attn);

  // output projection: fp32 out
  gemm256<false><<<dim3(64*4), dim3(1024), 163840, stream>>>(
      attn, wob, bo, bo, bo, out, out, out);
}

// Round 13
// 205.952 us; speedup vs baseline: 1.0366x; 1.0366x over previous
//
#include <hip/hip_runtime.h>
#include <hip/hip_bf16.h>
#include <stdint.h>

// Round 14: exact restore of R11 (best measured: 206.4 us total, QKV 113.5us,
// MfmaUtil 41%). R13's sched_barrier removal was neutral on the GEMM (same
// 113.5us / 40.4%) -- compiler already schedules across it; total delta was
// noise. R10-R13 bracketed the design space: 16 waves + counted vmcnt +
// 1 barrier/tile + 8-frag live set is the optimum of this structure family
// (908 TF at K=1024, above the documented m248 8-phase reference of 848).
// GEMM: 256x256 tile, 16 waves (4x4), 64x64 wave tile, A3+B2 ring 160KiB,
// period-6 unrolled slots, patch XCD map, T2 swizzle, vmcnt(2) counted (T4),
// setprio (T5), two sched_barrier(0) fences (stage-pin + read-phase split).
// attn chain: MFMA attn_norm (den folded as 5th B-column), bf16 kvT,
// merged cvt.
//
// ws layout (bytes):
//   xb   : [0, 32MB)  bf16 [M, C]   (reused as attn)
//   wqb  : 32MB + 2MB each: wkb, wvb, wob   (wq..wv contiguous = fused [3C, C])
//   q    : 40MB  k : 72MB  v : 104MB   bf16 [M, C]
//   kvp  : 136MB f32 [8][64][64][64];  ksp : +8MB f32 [8][64][64]
//   kvT  : 144MB+128KB  bf16 [64][80][64]  (640 KB)

#define B_ 4
#define T_ 4096
#define C_ 1024
#define H_ 16
#define D_ 64
#define M_ (B_*T_)
#define TCH 512
#define K_ 1024
#define NT_ (K_/64)          // 16 K-tiles of BK=64

using u16 = unsigned short;
using u32 = unsigned int;

typedef __attribute__((ext_vector_type(8))) short bf16x8;
typedef __attribute__((ext_vector_type(4))) float f32x4;

static __device__ __forceinline__ u16 f2bf(float f){
  u32 u = __float_as_uint(f);
  u32 r = (u + 0x7fffu + ((u >> 16) & 1u)) >> 16;   // RNE, no NaN here
  return (u16)r;
}
static __device__ __forceinline__ void unpack8(uint4 u, float* f){
  f[0]=__uint_as_float(u.x<<16); f[1]=__uint_as_float(u.x&0xffff0000u);
  f[2]=__uint_as_float(u.y<<16); f[3]=__uint_as_float(u.y&0xffff0000u);
  f[4]=__uint_as_float(u.z<<16); f[5]=__uint_as_float(u.z&0xffff0000u);
  f[6]=__uint_as_float(u.w<<16); f[7]=__uint_as_float(u.w&0xffff0000u);
}
static __device__ __forceinline__ void gload16(const u16* g, u16* l){
  __builtin_amdgcn_global_load_lds(
      (const __attribute__((address_space(1))) void*)g,
      (__attribute__((address_space(3))) void*)l, 16, 0, 0);
}

#define FENCE() asm volatile("" ::: "memory")
#define BAR() do { FENCE(); __builtin_amdgcn_s_barrier(); FENCE(); } while(0)

// ---------------- fp32 -> bf16 convert: x + 4 weights in ONE launch ----------
__global__ __launch_bounds__(256) void cvt_all(
    const float* __restrict__ x,
    const float* __restrict__ s0, const float* __restrict__ s1,
    const float* __restrict__ s2, const float* __restrict__ s3,
    u16* __restrict__ xb,
    u16* __restrict__ d0, u16* __restrict__ d1,
    u16* __restrict__ d2, u16* __restrict__ d3)
{
  const float* s; u16* d; int bi;
  if (blockIdx.x < 8192) { s = x; d = xb; bi = blockIdx.x; }
  else {
    const int seg = (blockIdx.x - 8192) >> 9;
    bi = (blockIdx.x - 8192) & 511;
    s = seg==0?s0:seg==1?s1:seg==2?s2:s3;
    d = seg==0?d0:seg==1?d1:seg==2?d2:d3;
  }
  const int i = (bi*256 + threadIdx.x) * 8;
  const float4 a = *(const float4*)(s + i);
  const float4 b = *(const float4*)(s + i + 4);
  uint4 o;
  o.x = (u32)f2bf(a.x) | ((u32)f2bf(a.y) << 16);
  o.y = (u32)f2bf(a.z) | ((u32)f2bf(a.w) << 16);
  o.z = (u32)f2bf(b.x) | ((u32)f2bf(b.y) << 16);
  o.w = (u32)f2bf(b.z) | ((u32)f2bf(b.w) << 16);
  *(uint4*)(d + i) = o;
}

// ---------------- 256x256 / BK=64 / 16-wave / A3+B2-ring MFMA GEMM -----------
// Y[M,N] = X[M,K] @ W[N,K]^T + b.  1024 threads = 16 waves (4M x 4N), wave
// tile 64x64.  LDS 160 KiB (u16 units): A slot s at s*16384 (s=0..2, halves
// +8192), B slot s at 49152 + s*16384 (s=0..1, halves +8192).
// T2 swizzle: logical 16B-chunk c of row r at phys chunk c^(r&7); staged via
// linear global_load_lds dest + inverse-swizzled global source.
// Per K-tile v (A slot v%3, B slot v%2), ONE barrier:
//   reads k0 (8, into a/b); stageB(v+1)->(v+1)%2; stageA(v+2)->(v+2)%3;
//   sched_barrier; setprio(1) 16 MFMA k0 setprio(0); sched_barrier;
//   reads k1 (8, SAME a/b regs); setprio(1) 16 MFMA k1 setprio(0);
//   vmcnt(2) [tail (0)/none]; BAR
// Live set: 8 frags (32 VGPR) + acc (64) + addr -> fits 128/wave, no spill.
// FIFO at tile end: outstanding = A(v+1), B(v+1), A(v+2) (6 gloads);
// vmcnt(2) drains A(v+1)+B(v+1), leaves A(v+2) flying (T4: never 0 in loop).
// WAR safety: a wave's reads of a slot complete at its lgkm wait (before its
// MFMAs, before it reaches the tile BAR); stages issue only after the prior
// BAR and target slots last read one tile earlier. Proven by R10/R11 passes.
template<bool FUSED>
__global__ __launch_bounds__(1024, 4) void gemm256(
    const u16* __restrict__ X, const u16* __restrict__ Wm,
    const float* __restrict__ b0, const float* __restrict__ b1,
    const float* __restrict__ b2,
    void* __restrict__ Y0, void* __restrict__ Y1, void* __restrict__ Y2)
{
  extern __shared__ __align__(16) u16 lds[];   // 163840 B
  const int tid  = threadIdx.x;
  const int lane = tid & 63, w = tid >> 6;
  const int wr = w >> 2, wc = w & 3;           // wave grid 4 x 4
  const int fr = lane & 15, hi = lane >> 4;

  // patch-based XCD mapping: 4bm x 4bn patches (~4MB working set per patch =
  // fits one XCD L2). Bijective: FUSED 768 = 8*6*16; !FUSED 256 = 8*2*16.
  const int xcd = blockIdx.x & 7;
  const int r   = blockIdx.x >> 3;
  const int ppx = gridDim.x >> 7;              // patches per XCD (6 or 2)
  const int patchIdx = xcd * ppx + (r >> 4);
  const int wi = r & 15;
  const int pm = FUSED ? (patchIdx & 15) : patchIdx;
  const int pn = FUSED ? (patchIdx >> 4) : 0;
  const int bm = pm*4 + (wi & 3);
  const int bn = pn*4 + (wi >> 2);

  // staging: thread t covers LDS bytes t*16 of a 128x64 half-tile;
  // row = t>>3 (0..127), phys chunk t&7 holds logical chunk (t&7)^(row&7).
  const int srow = tid >> 3;
  const int scc  = (tid & 7) ^ (srow & 7);
  const u16* gA = X  + (size_t)(bm*256 + srow)*K_ + scc*8;
  const u16* gB = Wm + (size_t)(bn*256 + srow)*K_ + scc*8;

  auto stageA = [&](int slot, int kt){
    const size_t ko = (size_t)kt * 64;
    gload16(gA + ko,                  lds + slot*16384 + tid*8);
    gload16(gA + (size_t)128*K_ + ko, lds + slot*16384 + 8192 + tid*8);
  };
  auto stageB = [&](int slot, int kt){
    const size_t ko = (size_t)kt * 64;
    gload16(gB + ko,                  lds + 49152 + slot*16384 + tid*8);
    gload16(gB + (size_t)128*K_ + ko, lds + 49152 + slot*16384 + 8192 + tid*8);
  };

  f32x4 acc[4][4] = {};
  const int cx0 = (hi ^ (fr & 7)) << 3;        // k-half 0 chunk (u16 offset)
  const int cx1 = ((4 + hi) ^ (fr & 7)) << 3;  // k-half 1 chunk
  // per-wave LDS fragment lane bases (slot/row-step added as immediates)
  const u16* Abase = lds + (wr >> 1)*8192 + ((wr & 1)*64 + fr)*64;
  const u16* Bbase = lds + 49152 + (wc >> 1)*8192 + ((wc & 1)*64 + fr)*64;

  // prologue FIFO: A(0)x2, B(0)x2, A(1)x2 -> vmcnt(2) drains A0,B0, leaves A1.
  // B(1) is staged at tile 0 (steady-state pattern).
  stageA(0,0); stageB(0,0);
  stageA(1,1);
  asm volatile("s_waitcnt vmcnt(2)" ::: "memory");
  BAR();

  // MODE: 0 = stage B(v+1)+A(v+2), vmcnt(2); 1 = stage B(v+1) only, vmcnt(0);
  //       2 = final (no stage, no wait, no BAR)
#define TILE(AS, BS, BSG, BKT, ASG, AKT, MODE) \
  { \
    bf16x8 a[4], b[4]; \
    _Pragma("unroll") \
    for (int i = 0; i < 4; ++i) a[i] = *(const bf16x8*)&Abase[(AS)*16384 + cx0 + i*1024]; \
    _Pragma("unroll") \
    for (int j = 0; j < 4; ++j) b[j] = *(const bf16x8*)&Bbase[(BS)*16384 + cx0 + j*1024]; \
    if (MODE != 2) stageB((BSG), (BKT)); \
    if (MODE == 0) stageA((ASG), (AKT)); \
    __builtin_amdgcn_sched_barrier(0); \
    __builtin_amdgcn_s_setprio(1); \
    _Pragma("unroll") \
    for (int i = 0; i < 4; ++i) \
      _Pragma("unroll") \
      for (int j = 0; j < 4; ++j) \
        acc[i][j] = __builtin_amdgcn_mfma_f32_16x16x32_bf16(a[i], b[j], acc[i][j], 0, 0, 0); \
    __builtin_amdgcn_s_setprio(0); \
    __builtin_amdgcn_sched_barrier(0); \
    _Pragma("unroll") \
    for (int i = 0; i < 4; ++i) a[i] = *(const bf16x8*)&Abase[(AS)*16384 + cx1 + i*1024]; \
    _Pragma("unroll") \
    for (int j = 0; j < 4; ++j) b[j] = *(const bf16x8*)&Bbase[(BS)*16384 + cx1 + j*1024]; \
    __builtin_amdgcn_s_setprio(1); \
    _Pragma("unroll") \
    for (int i = 0; i < 4; ++i) \
      _Pragma("unroll") \
      for (int j = 0; j < 4; ++j) \
        acc[i][j] = __builtin_amdgcn_mfma_f32_16x16x32_bf16(a[i], b[j], acc[i][j], 0, 0, 0); \
    __builtin_amdgcn_s_setprio(0); \
    if (MODE == 0)      asm volatile("s_waitcnt vmcnt(2)" ::: "memory"); \
    else if (MODE == 1) asm volatile("s_waitcnt vmcnt(0)" ::: "memory"); \
    if (MODE != 2) BAR(); \
  }

  // v = 0..15: A slot v%3, B slot v%2; stage B(v+1)->(v+1)%2, A(v+2)->(v+2)%3
  TILE(0,0, 1, 1, 2, 2, 0)   // v=0
  TILE(1,1, 0, 2, 0, 3, 0)   // v=1
  TILE(2,0, 1, 3, 1, 4, 0)   // v=2
  TILE(0,1, 0, 4, 2, 5, 0)   // v=3
  TILE(1,0, 1, 5, 0, 6, 0)   // v=4
  TILE(2,1, 0, 6, 1, 7, 0)   // v=5
  TILE(0,0, 1, 7, 2, 8, 0)   // v=6
  TILE(1,1, 0, 8, 0, 9, 0)   // v=7
  TILE(2,0, 1, 9, 1,10, 0)   // v=8
  TILE(0,1, 0,10, 2,11, 0)   // v=9
  TILE(1,0, 1,11, 0,12, 0)   // v=10
  TILE(2,1, 0,12, 1,13, 0)   // v=11
  TILE(0,0, 1,13, 2,14, 0)   // v=12
  TILE(1,1, 0,14, 0,15, 0)   // v=13
  TILE(2,0, 1,15, 0, 0, 1)   // v=14: stage B(15) only, drain all
  TILE(0,1, 0, 0, 0, 0, 2)   // v=15: final

#undef TILE

  // epilogue: C/D layout col = lane&15 (n), row = (lane>>4)*4 + reg (m).
  // j innermost: per (i,r2) the wave's stores cover one contiguous
  // 128B (bf16) / 256B (fp32) span -> full-line writes, no RMW.
  const int nloc = wc*64 + fr;
  if constexpr (FUSED) {
    const int sel  = bn >> 2;                  // uniform per block
    const int colb = (bn & 3)*256 + nloc;
    const float* bp = (sel == 0 ? b0 : sel == 1 ? b1 : b2);
    u16* Y = (u16*)(sel == 0 ? Y0 : sel == 1 ? Y1 : Y2);
    const bool elu = sel < 2;
    float bb[4];
    #pragma unroll
    for (int j = 0; j < 4; ++j) bb[j] = bp[colb + j*16];
    #pragma unroll
    for (int i = 0; i < 4; ++i) {
      #pragma unroll
      for (int r2 = 0; r2 < 4; ++r2) {
        const size_t row = (size_t)(bm*256 + wr*64 + i*16 + hi*4 + r2);
        u16* yp = Y + row*1024 + colb;
        #pragma unroll
        for (int j = 0; j < 4; ++j) {
          float vv = acc[i][j][r2] + bb[j];
          if (elu) vv = (vv > 0.0f) ? (vv + 1.0f) : __expf(vv);   // elu(x)+1
          yp[j*16] = f2bf(vv);
        }
      }
    }
  } else {
    const int n0 = bn*256 + nloc;
    float bb[4];
    #pragma unroll
    for (int j = 0; j < 4; ++j) bb[j] = b0[n0 + j*16];
    float* Y = (float*)Y0;
    #pragma unroll
    for (int i = 0; i < 4; ++i) {
      #pragma unroll
      for (int r2 = 0; r2 < 4; ++r2) {
        const size_t row = (size_t)(bm*256 + wr*64 + i*16 + hi*4 + r2);
        float* yp = Y + row*1024 + n0;
        #pragma unroll
        for (int j = 0; j < 4; ++j)
          yp[j*16] = acc[i][j][r2] + bb[j];
      }
    }
  }
}

// ---------------- kv partial (unchanged) -------------------------------------
__global__ __launch_bounds__(256) void kv_partial(
    const u16* __restrict__ Kb, const u16* __restrict__ Vb,
    float* __restrict__ kvp, float* __restrict__ ksp)
{
  const int tid = threadIdx.x;
  const int bh = blockIdx.x;
  const int b = bh >> 4, h = bh & 15;
  const int chunk = blockIdx.y;
  __shared__ float kbuf[32][68];
  __shared__ float vbuf[32][68];
  float acc[4][4] = {};
  float ksl = 0.0f;
  const int d0 = (tid >> 4) << 2, e0 = (tid & 15) << 2;
  const int lrow = tid >> 3, lcol = (tid & 7) << 3;

  for (int s = 0; s < TCH/32; ++s) {
    const int t = chunk*TCH + s*32;
    {
      const size_t base = ((size_t)(b*T_ + t + lrow))*C_ + h*64 + lcol;
      const uint4 ku = *(const uint4*)(Kb + base);
      const uint4 vu = *(const uint4*)(Vb + base);
      float kf[8], vf[8];
      unpack8(ku, kf); unpack8(vu, vf);
      #pragma unroll
      for (int j = 0; j < 8; ++j) { kbuf[lrow][lcol+j] = kf[j]; vbuf[lrow][lcol+j] = vf[j]; }
    }
    __syncthreads();
    if (tid < 64) {
      #pragma unroll
      for (int tt = 0; tt < 32; ++tt) ksl += kbuf[tt][tid];
    }
    #pragma unroll
    for (int tt = 0; tt < 32; ++tt) {
      const float4 ka = *(const float4*)&kbuf[tt][d0];
      const float4 va = *(const float4*)&vbuf[tt][e0];
      const float kr[4] = {ka.x, ka.y, ka.z, ka.w};
      const float vr[4] = {va.x, va.y, va.z, va.w};
      #pragma unroll
      for (int i = 0; i < 4; ++i)
        #pragma unroll
        for (int j = 0; j < 4; ++j)
          acc[i][j] = fmaf(kr[i], vr[j], acc[i][j]);
    }
    __syncthreads();
  }

  float* dst = kvp + ((size_t)(chunk*64 + bh))*4096;
  #pragma unroll
  for (int i = 0; i < 4; ++i)
    *(float4*)&dst[(d0+i)*64 + e0] = make_float4(acc[i][0], acc[i][1], acc[i][2], acc[i][3]);
  if (tid < 64) ksp[((size_t)(chunk*64 + bh))*64 + tid] = ksl;
}

// ---------------- kv reduce -> bf16 kvT[bh][80][64] (row 64 = ksum) ----------
__global__ __launch_bounds__(256) void kv_reduce(
    const float* __restrict__ kvp, const float* __restrict__ ksp,
    u16* __restrict__ kvT)
{
  const int idx = blockIdx.x*256 + threadIdx.x;
  if (idx < 262144) {                          // idx = bh*4096 + d*64 + e
    float s = 0.0f;
    #pragma unroll
    for (int c = 0; c < 8; ++c) s += kvp[(size_t)c*262144 + idx];
    const int bh = idx >> 12, d = (idx >> 6) & 63, e = idx & 63;
    kvT[(size_t)bh*5120 + e*64 + d] = f2bf(s);
  } else if (idx < 266240) {                   // bh*64 + d -> ksum row
    const int i2 = idx - 262144;
    float s = 0.0f;
    #pragma unroll
    for (int c = 0; c < 8; ++c) s += ksp[(size_t)c*4096 + i2];
    const int bh = i2 >> 6, d = i2 & 63;
    kvT[(size_t)bh*5120 + 4096 + d] = f2bf(s);
  } else if (idx < 266240 + 64*15*64) {        // zero rows 65..79
    const int i3 = idx - 266240;
    const int bh = i3 / 960, rd = i3 - bh*960;
    kvT[(size_t)bh*5120 + 4160 + rd] = 0;
  }
}

// ---------------- attn_norm via MFMA (unchanged) -----------------------------
__global__ __launch_bounds__(256) void attn_norm_mfma(
    const u16* __restrict__ Qb, const u16* __restrict__ kvT,
    u16* __restrict__ attn)
{
  __shared__ __align__(16) u16 qs[256*64];     // 32 KB
  const int tid = threadIdx.x;
  const int lane = tid & 63, w = tid >> 6;
  const int bh = blockIdx.x;
  const int b = bh >> 4, h = bh & 15;
  const int tt = blockIdx.y;                   // 16 tiles of 256 rows
  const int fr = lane & 15, hi = lane >> 4;

  // stage q tile: linear LDS dest, inverse-swizzled global source (rule #21)
  {
    const int srow = tid >> 3, scc = tid & 7;
    #pragma unroll
    for (int r = 0; r < 8; ++r) {
      const int row = r*32 + srow;
      const u16* src = Qb + ((size_t)(b*T_ + tt*256 + row))*C_ + h*64
                         + ((scc ^ (row & 7)) << 3);
      gload16(src, qs + tid*8 + r*2048);
    }
  }

  // B-fragments direct from global while staging is in flight
  const u16* kvb = kvT + (size_t)bh*5120;
  bf16x8 bv[5][2];
  #pragma unroll
  for (int j = 0; j < 5; ++j) {
    const int row = (j < 4) ? (j*16 + fr) : (64 + fr);
    bv[j][0] = *(const bf16x8*)&kvb[row*64 + hi*8];
    bv[j][1] = *(const bf16x8*)&kvb[row*64 + 32 + hi*8];
  }

  __syncthreads();                             // drains vmcnt: q tile visible

  f32x4 accN[4][4] = {};
  f32x4 accD[4] = {};
  #pragma unroll
  for (int kh = 0; kh < 2; ++kh) {
    const int cx = ((kh*4 + hi) ^ (fr & 7)) << 3;
    bf16x8 a[4];
    #pragma unroll
    for (int i = 0; i < 4; ++i)
      a[i] = *(const bf16x8*)&qs[(w*64 + i*16 + fr)*64 + cx];
    #pragma unroll
    for (int i = 0; i < 4; ++i) {
      #pragma unroll
      for (int j = 0; j < 4; ++j)
        accN[i][j] = __builtin_amdgcn_mfma_f32_16x16x32_bf16(a[i], bv[j][kh], accN[i][j], 0, 0, 0);
      accD[i] = __builtin_amdgcn_mfma_f32_16x16x32_bf16(a[i], bv[4][kh], accD[i], 0, 0, 0);
    }
  }

  // epilogue: den in col 0 (fr==0 lanes) of accD; broadcast within hi-group
  #pragma unroll
  for (int i = 0; i < 4; ++i) {
    #pragma unroll
    for (int r = 0; r < 4; ++r) {
      const float den = __shfl(accD[i][r], lane & 0x30);
      const float inv = 1.0f / fmaxf(den, 1e-6f);
      const size_t row = (size_t)(b*T_ + tt*256 + w*64 + i*16 + hi*4 + r);
      u16* yp = attn + row*1024 + h*64 + fr;
      #pragma unroll
      for (int j = 0; j < 4; ++j)
        yp[j*16] = f2bf(accN[i][j][r] * inv);
    }
  }
}

extern "C" void kernel_launch(void* const* d_in, const int* in_sizes, int n_in,
                              void* d_out, int out_size, void* d_ws, size_t ws_size,
                              hipStream_t stream)
{
  (void)in_sizes; (void)n_in; (void)out_size; (void)ws_size;
  const float* x  = (const float*)d_in[0];
  const float* Wq = (const float*)d_in[1];
  const float* bq = (const float*)d_in[2];
  const float* Wk = (const float*)d_in[3];
  const float* bk = (const float*)d_in[4];
  const float* Wv = (const float*)d_in[5];
  const float* bv = (const float*)d_in[6];
  const float* Wo = (const float*)d_in[7];
  const float* bo = (const float*)d_in[8];
  float* out = (float*)d_out;
  char* ws = (char*)d_ws;

  const size_t MB = 1024*1024;
  u16*   xb   = (u16*)(ws);                       // 32MB
  u16*   wqb  = (u16*)(ws + 32*MB);               // 2MB each; wq..wv = fused [3072,1024]
  u16*   wkb  = (u16*)(ws + 34*MB);
  u16*   wvb  = (u16*)(ws + 36*MB);
  u16*   wob  = (u16*)(ws + 38*MB);
  u16*   q    = (u16*)(ws + 40*MB);               // 32MB
  u16*   k    = (u16*)(ws + 72*MB);               // 32MB
  u16*   v    = (u16*)(ws + 104*MB);              // 32MB
  float* kvp  = (float*)(ws + 136*MB);            // 8MB
  float* ksp  = (float*)(ws + 144*MB);            // 128KB
  u16*   kvT  = (u16*)(ws + 144*MB + 131072);     // 640KB bf16 [64][80][64]
  u16*   attn = xb;  // xb dead after the fused QKV GEMM

  static bool s_attr_done = false;
  if (!s_attr_done) {
    (void)hipFuncSetAttribute(reinterpret_cast<const void*>(gemm256<true>),
                              hipFuncAttributeMaxDynamicSharedMemorySize, 163840);
    (void)hipFuncSetAttribute(reinterpret_cast<const void*>(gemm256<false>),
                              hipFuncAttributeMaxDynamicSharedMemorySize, 163840);
    s_attr_done = true;
  }

  dim3 blk(256);
  // x: 8192 blocks; 4 weights: 512 blocks each
  cvt_all<<<dim3(8192 + 4*512), blk, 0, stream>>>(
      x, Wq, Wk, Wv, Wo, xb, wqb, wkb, wvb, wob);

  // fused QKV projection: Y[16384, 3072] split into q/k/v, ELU+1 on q,k
  gemm256<true><<<dim3(64*12), dim3(1024), 163840, stream>>>(
      xb, wqb, bq, bk, bv, q, k, v);

  kv_partial<<<dim3(B_*H_, T_/TCH), blk, 0, stream>>>(k, v, kvp, ksp);
  kv_reduce<<<dim3(1280), blk, 0, stream>>>(kvp, ksp, kvT);
  attn_norm_mfma<<<dim3(B_*H_, T_/256), blk, 0, stream>>>(q, kvT, attn);

  // output projection: fp32 out
  gemm256<false><<<dim3(64*4), dim3(1024), 163840, stream>>>(
      attn, wob, bo, bo, bo, out, out, out);
}